// Round 1
// baseline (155.428 us; speedup 1.0000x reference)
//
#include <hip/hip_runtime.h>
#include <cstdint>
#include <cstddef>

#define NB 4
#define NG 8
#define NCELL 331776   // 48*48*48*3
#define KTOP 800
#define NREP 8         // global histogram replicas to spread atomic traffic
#define CAP 16384      // per-batch candidate buffer capacity (expected ~7.4k)
#define CPT 4          // cells per thread in main (ILP chains)
#define MBLK 324       // main blocks per batch: 324 * 256 * 4 = NCELL

struct WsHeader {
  float pos_sum[NB];
  float reg_sum[NB];
  int   npos[NB];
  int   neg_cnt[NB];
  float neg_sum[NB];
  int   done;
  int   bucket_cnt[NB][16];     // [b][0]=candidate count, [b][1]=blocks-done counter
  unsigned int hist[NB][NREP][256];
};

__device__ __forceinline__ float softplus0(float x) {
  // _bce_logits(x, 0) = max(x,0) + log1p(exp(-|x|))
  return fmaxf(x, 0.f) + log1pf(expf(-fabsf(x)));
}
__device__ __forceinline__ unsigned int f2key(float f) {
  unsigned int u = __float_as_uint(f);
  return (u & 0x80000000u) ? ~u : (u | 0x80000000u);
}
__device__ __forceinline__ float key2f(unsigned int k) {
  unsigned int u = (k & 0x80000000u) ? (k & 0x7fffffffu) : ~k;
  return __uint_as_float(u);
}
__device__ __forceinline__ float sl1(float x) {
  float ax = fabsf(x);
  return ax < 1.f ? 0.5f * x * x : ax - 0.5f;
}

// Per-cell loss terms + dense key write + top-byte histogram.
// 4 independent cells per thread => 4 overlapped load/compute chains (latency
// hiding); LDS-hist zero/flush and barriers amortized 4x. Direct global loads:
// the stride-20B conf pattern is L1-absorbed (measured: LDS staging neutral, R8).
__global__ __launch_bounds__(256) void main_kernel(const float* __restrict__ pred,
                                                   const float* __restrict__ tgt,
                                                   WsHeader* __restrict__ ws,
                                                   unsigned int* __restrict__ keys) {
  __shared__ float gt[NG * 4];
  __shared__ unsigned int lhist[4 * 257];      // 4 replicas, stride 257
  __shared__ float s_psum, s_rsum;
  __shared__ int s_np;
  const int b = blockIdx.y;
  const int tid = threadIdx.x;
  const int cell0 = blockIdx.x * (256 * CPT);  // 1024 consecutive cells per block

  if (tid < NG * 4) gt[tid] = tgt[b * NG * 4 + tid];
  for (int e = tid; e < 4 * 257; e += 256) lhist[e] = 0u;
  if (tid == 0) { s_psum = 0.f; s_rsum = 0.f; s_np = 0; }
  __syncthreads();

  const float anch[3] = {5.f, 10.f, 20.f};
  const float* pb = pred + (size_t)b * NCELL * 5;

  // issue all CPT conf loads up-front (independent chains)
  float conf[CPT];
#pragma unroll
  for (int j = 0; j < CPT; ++j)
    conf[j] = pb[(size_t)(cell0 + j * 256 + tid) * 5];

#pragma unroll
  for (int j = 0; j < CPT; ++j) {
    const int i = cell0 + j * 256 + tid;
    int a = i % 3; int t = i / 3;
    int w = t % 48; t /= 48;
    int h = t % 48; int d = t / 48;
    const float cx = w * 4.f + 2.f, cy = h * 4.f + 2.f, cz = d * 4.f + 2.f;
    const float an = anch[a];
    const float r1 = an * 0.5f;
    const float an3 = an * an * an;

    float best = -1.f; int arg = 0;
#pragma unroll
    for (int g = 0; g < NG; ++g) {
      float gx = gt[g * 4 + 0], gy = gt[g * 4 + 1], gz = gt[g * 4 + 2], gd = gt[g * 4 + 3];
      float r2 = gd * 0.5f;
      float ix = fmaxf(fminf(cx + r1, gx + r2) - fmaxf(cx - r1, gx - r2), 0.f);
      float iy = fmaxf(fminf(cy + r1, gy + r2) - fmaxf(cy - r1, gy - r2), 0.f);
      float iz = fmaxf(fminf(cz + r1, gz + r2) - fmaxf(cz - r1, gz - r2), 0.f);
      float iv = (ix * iy) * iz;
      float un = (an3 + gd * gd * gd) - iv;
      float iou = iv / (un + 1e-6f);
      if (iou > best) { best = iou; arg = g; }   // strict > == first-argmax
    }
    const bool pos = best > 0.5f;
    const bool neg = best < 0.02f;
    const float cf = conf[j];

    unsigned int key = 0u;   // sentinel: -NaN bit pattern, unreachable as real key
    if (neg) {
      key = f2key(cf);
      atomicAdd(&lhist[(tid & 3) * 257 + (key >> 24)], 1u);
    }
    keys[(size_t)b * NCELL + i] = key;

    if (pos) {
      const size_t base = (size_t)i * 5;
      float bce1 = fmaxf(cf, 0.f) - cf + log1pf(expf(-fabsf(cf)));
      float mgx = gt[arg * 4 + 0], mgy = gt[arg * 4 + 1], mgz = gt[arg * 4 + 2], mgd = gt[arg * 4 + 3];
      float t0 = (mgx - cx) / an, t1 = (mgy - cy) / an, t2 = (mgz - cz) / an;
      float t3 = logf(mgd / an);
      float d0 = pb[base + 1] - t0;
      float d1 = pb[base + 2] - t1;
      float d2 = pb[base + 3] - t2;
      float d3 = pb[base + 4] - t3;
      float rl = sl1(d0) + sl1(d1) + sl1(d2) + sl1(d3);
      atomicAdd(&s_psum, bce1);
      atomicAdd(&s_rsum, rl);
      atomicAdd(&s_np, 1);
    }
  }
  __syncthreads();

  unsigned int c = lhist[tid] + lhist[257 + tid] + lhist[514 + tid] + lhist[771 + tid];
  if (c) atomicAdd(&ws->hist[b][blockIdx.x & (NREP - 1)][tid], c);
  if (tid == 0 && s_np > 0) {        // rare: fire-and-forget, most blocks skip
    atomicAdd(&ws->pos_sum[b], s_psum);
    atomicAdd(&ws->reg_sum[b], s_rsum);
    atomicAdd(&ws->npos[b], s_np);
  }
}

// Grid-parallel compact + fused finisher.
// Each block redundantly finds the 8-bit threshold bucket j from the global
// histogram (wave-shfl suffix scan, 3 barriers), compacts matching keys into
// the bucket buffer (wave-shfl prefix scan, 2 barriers), then the LAST block
// per batch (device-fence election) runs the exact top-KTOP radix refinement
// and the neg-loss sum; the last finisher overall does the final combine.
__global__ __launch_bounds__(256) void compact_kernel(const unsigned int* __restrict__ keys,
                                                      WsHeader* __restrict__ ws,
                                                      unsigned int* __restrict__ bucket,
                                                      float* __restrict__ out) {
  const int b = blockIdx.y;
  const int tid = threadIdx.x;
  const int lane = tid & 63;
  const int wvi = tid >> 6;
  __shared__ unsigned int A[256];
  __shared__ unsigned int h[256];
  __shared__ unsigned int wtot[4];
  __shared__ float wred[4];
  __shared__ int sh_j, sh_base, sh_lastb, sh_last;

  // ---- phase 1: global hist -> suffix scan -> threshold bucket j ----
  unsigned int s = 0;
#pragma unroll
  for (int r = 0; r < NREP; ++r) s += ws->hist[b][r][tid];
  unsigned int v = s;
#pragma unroll
  for (int o = 1; o < 64; o <<= 1) {               // in-wave inclusive suffix scan
    unsigned int t = __shfl_down(v, o);
    if (lane + o < 64) v += t;
  }
  if (lane == 0) wtot[wvi] = v;                    // wave total
  __syncthreads();
  unsigned int carry = 0;
#pragma unroll
  for (int w2 = 0; w2 < 4; ++w2) carry += (w2 > wvi) ? wtot[w2] : 0u;
  v += carry;
  A[tid] = v;
  __syncthreads();
  const int M = (int)A[0];
  const bool ta = (M < KTOP);
  if (!ta && A[tid] >= (unsigned)KTOP && (tid == 255 || A[tid + 1] < (unsigned)KTOP))
    sh_j = tid;
  __syncthreads();
  const unsigned int jthr = ta ? 0u : (unsigned int)sh_j;
  int k0 = 0;
  if (!ta) {
    int above = (jthr < 255u) ? (int)A[jthr + 1] : 0;
    k0 = KTOP - above;
  }

  // ---- phase 2: compact keys with top byte >= j ----
  const uint4* k4 = (const uint4*)(keys + (size_t)b * NCELL);
  const int base4 = blockIdx.x * 1024;   // 81 blocks x 1024 uint4 = NCELL/4
  int cnt = 0;
#pragma unroll
  for (int it = 0; it < 4; ++it) {
    uint4 kk = k4[base4 + it * 256 + tid];
    cnt += (kk.x != 0u && (kk.x >> 24) >= jthr);
    cnt += (kk.y != 0u && (kk.y >> 24) >= jthr);
    cnt += (kk.z != 0u && (kk.z >> 24) >= jthr);
    cnt += (kk.w != 0u && (kk.w >> 24) >= jthr);
  }
  unsigned int pv = (unsigned int)cnt;
#pragma unroll
  for (int o = 1; o < 64; o <<= 1) {               // in-wave inclusive prefix scan
    unsigned int t = __shfl_up(pv, o);
    if (lane >= o) pv += t;
  }
  if (lane == 63) wtot[wvi] = pv;                  // safe: old wtot reads done pre-A-barrier
  __syncthreads();
  unsigned int pcarry = 0, ptot = 0;
#pragma unroll
  for (int w2 = 0; w2 < 4; ++w2) {
    ptot += wtot[w2];
    pcarry += (w2 < wvi) ? wtot[w2] : 0u;
  }
  if (tid == 0) sh_base = ptot ? atomicAdd(&ws->bucket_cnt[b][0], (int)ptot) : 0;
  __syncthreads();
  int off = sh_base + (int)(pv + pcarry) - cnt;    // exclusive rank + block base
#pragma unroll
  for (int it = 0; it < 4; ++it) {
    uint4 kk = k4[base4 + it * 256 + tid];
    unsigned int kv;
    kv = kk.x; if (kv != 0u && (kv >> 24) >= jthr) { if (off < CAP) bucket[(size_t)b * CAP + off] = kv; ++off; }
    kv = kk.y; if (kv != 0u && (kv >> 24) >= jthr) { if (off < CAP) bucket[(size_t)b * CAP + off] = kv; ++off; }
    kv = kk.z; if (kv != 0u && (kv >> 24) >= jthr) { if (off < CAP) bucket[(size_t)b * CAP + off] = kv; ++off; }
    kv = kk.w; if (kv != 0u && (kv >> 24) >= jthr) { if (off < CAP) bucket[(size_t)b * CAP + off] = kv; ++off; }
  }

  // ---- phase 3: last-block-per-batch election ----
  __threadfence();                                  // release: bucket + count visible
  if (tid == 0) {
    int old = atomicAdd(&ws->bucket_cnt[b][1], 1);
    sh_lastb = (old == (int)gridDim.x - 1) ? 1 : 0;
  }
  __syncthreads();
  if (!sh_lastb) return;
  __threadfence();                                  // acquire: see all blocks' buckets

  // ---- phase 4 (finisher, 1 block/batch): exact top-KTOP radix refinement ----
  int m = ws->bucket_cnt[b][0]; if (m > CAP) m = CAP;
  const unsigned int* kb = bucket + (size_t)b * CAP;

  unsigned int T = 0u;
  int k = 0;
  if (!ta) {
    unsigned int P = jthr << 24;
    k = k0;
    for (int pass = 1; pass < 4; ++pass) {
      const int sh = 24 - 8 * pass;
      const unsigned int hiMask = 0xFFFFFFFFu << (sh + 8);
      h[tid] = 0u;
      __syncthreads();
      for (int i = tid; i < m; i += 256) {
        unsigned int kv = kb[i];
        if (((kv ^ P) & hiMask) == 0u) atomicAdd(&h[(kv >> sh) & 255u], 1u);
      }
      __syncthreads();
      unsigned int vv = h[tid];
#pragma unroll
      for (int o = 1; o < 64; o <<= 1) {
        unsigned int t = __shfl_down(vv, o);
        if (lane + o < 64) vv += t;
      }
      if (lane == 0) wtot[wvi] = vv;
      __syncthreads();
      unsigned int cr = 0;
#pragma unroll
      for (int w2 = 0; w2 < 4; ++w2) cr += (w2 > wvi) ? wtot[w2] : 0u;
      vv += cr;
      A[tid] = vv;
      __syncthreads();
      if (A[tid] >= (unsigned)k && (tid == 255 || A[tid + 1] < (unsigned)k))
        sh_j = tid;
      __syncthreads();
      const int j = sh_j;
      k -= (j == 255) ? 0 : (int)A[j + 1];          // remove strictly-greater bins
      P |= ((unsigned int)j) << sh;
      // no trailing barrier: next pass's h-zero + barrier orders A/sh_j reuse
    }
    T = P;   // exact threshold key; k = #ties to take at T
  }

  // ---- phase 5: neg-loss sum over survivors ----
  float fv = 0.f;
  for (int i = tid; i < m; i += 256) {
    unsigned int kv = kb[i];
    if (ta || kv > T) fv += softplus0(key2f(kv));
  }
#pragma unroll
  for (int o = 32; o > 0; o >>= 1) fv += __shfl_down(fv, o);
  if (lane == 0) wred[wvi] = fv;
  __syncthreads();
  if (tid == 0) {
    float sum = wred[0] + wred[1] + wred[2] + wred[3];
    if (!ta) sum += (float)k * softplus0(key2f(T));
    ws->neg_sum[b] = sum;
    ws->neg_cnt[b] = M;
    __threadfence();
    int old = atomicAdd(&ws->done, 1);
    sh_last = (old == NB - 1) ? 1 : 0;
  }
  __syncthreads();

  // ---- phase 6: last finisher overall does the combine ----
  if (sh_last && tid == 0) {
    __threadfence();
    float cls_s = 0.f, reg_s = 0.f, np_s = 0.f;
    for (int bb = 0; bb < NB; ++bb) {
      int np = ws->npos[bb];
      float pos_l = (np > 0) ? 5.f * ws->pos_sum[bb] / (float)np : 0.f;
      int Mb = ws->neg_cnt[bb];
      float kcnt = fminf((float)Mb, (float)KTOP);
      float neg_l = (kcnt > 0.f) ? ws->neg_sum[bb] / fmaxf(kcnt, 1.f) : 0.f;
      float reg_l = (np > 0) ? ws->reg_sum[bb] / (4.f * (float)np) : 0.f;
      cls_s += pos_l + neg_l;
      reg_s += reg_l;
      np_s += (float)np;
    }
    float cls = cls_s * 0.25f;
    float reg = reg_s * 0.25f;
    out[0] = cls + 0.5f * reg;
    out[1] = cls;
    out[2] = reg;
    out[3] = np_s;
  }
}

extern "C" void kernel_launch(void* const* d_in, const int* in_sizes, int n_in,
                              void* d_out, int out_size, void* d_ws, size_t ws_size,
                              hipStream_t stream) {
  const float* pred = (const float*)d_in[0];
  const float* tgt  = (const float*)d_in[1];
  WsHeader* ws = (WsHeader*)d_ws;
  char* base = (char*)d_ws + ((sizeof(WsHeader) + 255) / 256) * 256;
  unsigned int* keys = (unsigned int*)base;
  unsigned int* bucket = (unsigned int*)(base + (size_t)NB * NCELL * 4);
  float* out = (float*)d_out;

  hipMemsetAsync(d_ws, 0, sizeof(WsHeader), stream);
  hipLaunchKernelGGL(main_kernel, dim3(MBLK, NB), dim3(256), 0, stream, pred, tgt, ws, keys);
  hipLaunchKernelGGL(compact_kernel, dim3(81, NB), dim3(256), 0, stream, keys, ws, bucket, out);
}

// Round 2
// 108.180 us; speedup vs baseline: 1.4368x; 1.4368x over previous
//
#include <hip/hip_runtime.h>
#include <cstdint>
#include <cstddef>

#define NB 4
#define NG 8
#define NCELL 331776   // 48*48*48*3
#define KTOP 800
#define NREP 8         // global histogram replicas to spread atomic traffic
#define CAP 16384      // per-batch candidate buffer capacity (expected ~7.4k)
#define LCAP 12288     // candidates cached in LDS when m <= LCAP (48 KB)
#define CPT 4          // cells per thread in main (ILP chains)
#define MBLK 324       // main blocks per batch: 324 * 256 * 4 = NCELL

struct WsHeader {
  float pos_sum[NB];
  float reg_sum[NB];
  int   npos[NB];
  int   neg_cnt[NB];
  int   take_all[NB];
  int   prefix8[NB];            // top-byte threshold bucket j
  int   k_rem[NB];              // KTOP - count(top byte > j)
  float neg_sum[NB];
  int   done;
  int   bucket_cnt[NB][16];     // one cacheline per batch
  unsigned int hist[NB][NREP][256];
};

__device__ __forceinline__ float softplus0(float x) {
  // _bce_logits(x, 0) = max(x,0) + log1p(exp(-|x|))
  return fmaxf(x, 0.f) + log1pf(expf(-fabsf(x)));
}
__device__ __forceinline__ unsigned int f2key(float f) {
  unsigned int u = __float_as_uint(f);
  return (u & 0x80000000u) ? ~u : (u | 0x80000000u);
}
__device__ __forceinline__ float key2f(unsigned int k) {
  unsigned int u = (k & 0x80000000u) ? (k & 0x7fffffffu) : ~k;
  return __uint_as_float(u);
}
__device__ __forceinline__ float sl1(float x) {
  float ax = fabsf(x);
  return ax < 1.f ? 0.5f * x * x : ax - 0.5f;
}

// Per-cell loss terms + dense key write + top-byte histogram.
// 4 independent cells per thread => 4 overlapped load/compute chains (latency
// hiding); LDS-hist zero/flush and barriers amortized 4x. Direct global loads:
// the stride-20B conf pattern is L1-absorbed (measured: LDS staging neutral, R8).
// NOTE (R1 lesson): no device-scope fences in this wide kernel — cross-XCD
// visibility of keys/hist comes from the kernel boundary.
__global__ __launch_bounds__(256) void main_kernel(const float* __restrict__ pred,
                                                   const float* __restrict__ tgt,
                                                   WsHeader* __restrict__ ws,
                                                   unsigned int* __restrict__ keys) {
  __shared__ float gt[NG * 4];
  __shared__ unsigned int lhist[4 * 257];      // 4 replicas, stride 257
  __shared__ float s_psum, s_rsum;
  __shared__ int s_np;
  const int b = blockIdx.y;
  const int tid = threadIdx.x;
  const int cell0 = blockIdx.x * (256 * CPT);  // 1024 consecutive cells per block

  if (tid < NG * 4) gt[tid] = tgt[b * NG * 4 + tid];
  for (int e = tid; e < 4 * 257; e += 256) lhist[e] = 0u;
  if (tid == 0) { s_psum = 0.f; s_rsum = 0.f; s_np = 0; }
  __syncthreads();

  const float anch[3] = {5.f, 10.f, 20.f};
  const float* pb = pred + (size_t)b * NCELL * 5;

  // issue all CPT conf loads up-front (independent chains)
  float conf[CPT];
#pragma unroll
  for (int j = 0; j < CPT; ++j)
    conf[j] = pb[(size_t)(cell0 + j * 256 + tid) * 5];

#pragma unroll
  for (int j = 0; j < CPT; ++j) {
    const int i = cell0 + j * 256 + tid;
    int a = i % 3; int t = i / 3;
    int w = t % 48; t /= 48;
    int h = t % 48; int d = t / 48;
    const float cx = w * 4.f + 2.f, cy = h * 4.f + 2.f, cz = d * 4.f + 2.f;
    const float an = anch[a];
    const float r1 = an * 0.5f;
    const float an3 = an * an * an;

    float best = -1.f; int arg = 0;
#pragma unroll
    for (int g = 0; g < NG; ++g) {
      float gx = gt[g * 4 + 0], gy = gt[g * 4 + 1], gz = gt[g * 4 + 2], gd = gt[g * 4 + 3];
      float r2 = gd * 0.5f;
      float ix = fmaxf(fminf(cx + r1, gx + r2) - fmaxf(cx - r1, gx - r2), 0.f);
      float iy = fmaxf(fminf(cy + r1, gy + r2) - fmaxf(cy - r1, gy - r2), 0.f);
      float iz = fmaxf(fminf(cz + r1, gz + r2) - fmaxf(cz - r1, gz - r2), 0.f);
      float iv = (ix * iy) * iz;
      float un = (an3 + gd * gd * gd) - iv;
      float iou = iv / (un + 1e-6f);
      if (iou > best) { best = iou; arg = g; }   // strict > == first-argmax
    }
    const bool pos = best > 0.5f;
    const bool neg = best < 0.02f;
    const float cf = conf[j];

    unsigned int key = 0u;   // sentinel: -NaN bit pattern, unreachable as real key
    if (neg) {
      key = f2key(cf);
      atomicAdd(&lhist[(tid & 3) * 257 + (key >> 24)], 1u);
    }
    keys[(size_t)b * NCELL + i] = key;

    if (pos) {
      const size_t base = (size_t)i * 5;
      float bce1 = fmaxf(cf, 0.f) - cf + log1pf(expf(-fabsf(cf)));
      float mgx = gt[arg * 4 + 0], mgy = gt[arg * 4 + 1], mgz = gt[arg * 4 + 2], mgd = gt[arg * 4 + 3];
      float t0 = (mgx - cx) / an, t1 = (mgy - cy) / an, t2 = (mgz - cz) / an;
      float t3 = logf(mgd / an);
      float d0 = pb[base + 1] - t0;
      float d1 = pb[base + 2] - t1;
      float d2 = pb[base + 3] - t2;
      float d3 = pb[base + 4] - t3;
      float rl = sl1(d0) + sl1(d1) + sl1(d2) + sl1(d3);
      atomicAdd(&s_psum, bce1);
      atomicAdd(&s_rsum, rl);
      atomicAdd(&s_np, 1);
    }
  }
  __syncthreads();

  unsigned int c = lhist[tid] + lhist[257 + tid] + lhist[514 + tid] + lhist[771 + tid];
  if (c) atomicAdd(&ws->hist[b][blockIdx.x & (NREP - 1)][tid], c);
  if (tid == 0 && s_np > 0) {        // rare: fire-and-forget, most blocks skip
    atomicAdd(&ws->pos_sum[b], s_psum);
    atomicAdd(&ws->reg_sum[b], s_rsum);
    atomicAdd(&ws->npos[b], s_np);
  }
}

// Grid-parallel: each block redundantly finds the 8-bit threshold bucket j from
// the histogram (wave-shfl suffix scan, 3 barriers), then compacts keys with
// top8 >= j into the small bucket buffer (wave-shfl prefix scan, 2 barriers).
// Publishes j and k_rem so final can skip its degenerate radix pass 0.
__global__ __launch_bounds__(256) void compact_kernel(const unsigned int* __restrict__ keys,
                                                      WsHeader* __restrict__ ws,
                                                      unsigned int* __restrict__ bucket) {
  const int b = blockIdx.y;
  const int tid = threadIdx.x;
  const int lane = tid & 63;
  const int wvi = tid >> 6;
  __shared__ unsigned int A[256];
  __shared__ unsigned int wtot[4];
  __shared__ int sh_j, sh_base;

  // ---- phase 1: global hist -> suffix scan -> threshold bucket j ----
  unsigned int s = 0;
#pragma unroll
  for (int r = 0; r < NREP; ++r) s += ws->hist[b][r][tid];
  unsigned int v = s;
#pragma unroll
  for (int o = 1; o < 64; o <<= 1) {               // in-wave inclusive suffix scan
    unsigned int t = __shfl_down(v, o);
    if (lane + o < 64) v += t;
  }
  if (lane == 0) wtot[wvi] = v;                    // wave total
  __syncthreads();
  unsigned int carry = 0;
#pragma unroll
  for (int w2 = 0; w2 < 4; ++w2) carry += (w2 > wvi) ? wtot[w2] : 0u;
  v += carry;
  A[tid] = v;
  __syncthreads();
  const int M = (int)A[0];
  const bool ta = (M < KTOP);
  if (!ta && A[tid] >= (unsigned)KTOP && (tid == 255 || A[tid + 1] < (unsigned)KTOP))
    sh_j = tid;
  __syncthreads();
  const unsigned int jthr = ta ? 0u : (unsigned int)sh_j;
  if (tid == 0 && blockIdx.x == 0) {
    ws->neg_cnt[b] = M;
    ws->take_all[b] = ta ? 1 : 0;
    ws->prefix8[b] = (int)jthr;
    int above = (!ta && jthr < 255u) ? (int)A[jthr + 1] : 0;
    ws->k_rem[b] = ta ? 0 : (KTOP - above);
  }

  // ---- phase 2: compact keys with top byte >= j ----
  const uint4* k4 = (const uint4*)(keys + (size_t)b * NCELL);
  const int base4 = blockIdx.x * 1024;   // 81 blocks x 1024 uint4 = NCELL/4
  int cnt = 0;
#pragma unroll
  for (int it = 0; it < 4; ++it) {
    uint4 kk = k4[base4 + it * 256 + tid];
    cnt += (kk.x != 0u && (kk.x >> 24) >= jthr);
    cnt += (kk.y != 0u && (kk.y >> 24) >= jthr);
    cnt += (kk.z != 0u && (kk.z >> 24) >= jthr);
    cnt += (kk.w != 0u && (kk.w >> 24) >= jthr);
  }
  unsigned int pv = (unsigned int)cnt;
#pragma unroll
  for (int o = 1; o < 64; o <<= 1) {               // in-wave inclusive prefix scan
    unsigned int t = __shfl_up(pv, o);
    if (lane >= o) pv += t;
  }
  if (lane == 63) wtot[wvi] = pv;                  // safe: phase-1 wtot reads done pre-A-barrier
  __syncthreads();
  unsigned int pcarry = 0, ptot = 0;
#pragma unroll
  for (int w2 = 0; w2 < 4; ++w2) {
    ptot += wtot[w2];
    pcarry += (w2 < wvi) ? wtot[w2] : 0u;
  }
  if (tid == 0) sh_base = ptot ? atomicAdd(&ws->bucket_cnt[b][0], (int)ptot) : 0;
  __syncthreads();
  int off = sh_base + (int)(pv + pcarry) - cnt;    // exclusive rank + block base
#pragma unroll
  for (int it = 0; it < 4; ++it) {
    uint4 kk = k4[base4 + it * 256 + tid];
    unsigned int kv;
    kv = kk.x; if (kv != 0u && (kv >> 24) >= jthr) { if (off < CAP) bucket[(size_t)b * CAP + off] = kv; ++off; }
    kv = kk.y; if (kv != 0u && (kv >> 24) >= jthr) { if (off < CAP) bucket[(size_t)b * CAP + off] = kv; ++off; }
    kv = kk.z; if (kv != 0u && (kv >> 24) >= jthr) { if (off < CAP) bucket[(size_t)b * CAP + off] = kv; ++off; }
    kv = kk.w; if (kv != 0u && (kv >> 24) >= jthr) { if (off < CAP) bucket[(size_t)b * CAP + off] = kv; ++off; }
  }
}

// One block per batch: exact top-KTOP among the ~7.4k candidates.
// Radix starts at pass 1 (pass-0 bucket j + k_rem come from compact), candidates
// cached in LDS. Wave-shfl suffix scans (3 barriers/pass vs 33 for tree scan).
// Last block to finish also does the final combine.
__global__ __launch_bounds__(1024) void final_kernel(const unsigned int* __restrict__ bucket,
                                                     WsHeader* __restrict__ ws,
                                                     float* __restrict__ out) {
  const int b = blockIdx.x;
  const int tid = threadIdx.x;
  const int lane = tid & 63;
  const int wvi = tid >> 6;
  __shared__ unsigned int skeys[LCAP];
  __shared__ unsigned int h[256];
  __shared__ unsigned int A[256];
  __shared__ unsigned int wtot[4];
  __shared__ int sh_j;
  __shared__ float wred[16];
  __shared__ int sh_last;

  int m = ws->bucket_cnt[b][0]; if (m > CAP) m = CAP;
  const bool ta = ws->take_all[b] != 0;
  const unsigned int* kb = bucket + (size_t)b * CAP;
  const bool useLds = (m <= LCAP);
  if (useLds)
    for (int i = tid; i < m; i += 1024) skeys[i] = kb[i];
  __syncthreads();

  unsigned int T = 0u;
  int k = 0;
  if (!ta) {
    unsigned int P = ((unsigned int)ws->prefix8[b]) << 24;
    k = ws->k_rem[b];
    for (int pass = 1; pass < 4; ++pass) {
      const int sh = 24 - 8 * pass;
      const unsigned int hiMask = 0xFFFFFFFFu << (sh + 8);
      if (tid < 256) h[tid] = 0u;
      __syncthreads();
      for (int i = tid; i < m; i += 1024) {
        unsigned int kv = useLds ? skeys[i] : kb[i];
        if (((kv ^ P) & hiMask) == 0u) atomicAdd(&h[(kv >> sh) & 255u], 1u);
      }
      __syncthreads();
      unsigned int vv = 0;
      if (tid < 256) {                             // waves 0-3: in-wave suffix scan
        vv = h[tid];
#pragma unroll
        for (int o = 1; o < 64; o <<= 1) {
          unsigned int t = __shfl_down(vv, o);
          if (lane + o < 64) vv += t;
        }
        if (lane == 0) wtot[wvi] = vv;
      }
      __syncthreads();
      if (tid < 256) {
        unsigned int cr = 0;
#pragma unroll
        for (int w2 = 0; w2 < 4; ++w2) cr += (w2 > wvi) ? wtot[w2] : 0u;
        vv += cr;
        A[tid] = vv;
      }
      __syncthreads();
      if (tid < 256 && A[tid] >= (unsigned)k && (tid == 255 || A[tid + 1] < (unsigned)k))
        sh_j = tid;
      __syncthreads();
      const int j = sh_j;
      k -= (j == 255) ? 0 : (int)A[j + 1];   // remove strictly-greater bins
      P |= ((unsigned int)j) << sh;
      // no trailing barrier: next pass's h-zero barrier orders A/sh_j/wtot reuse
    }
    T = P;   // exact threshold key; k = #ties to take at T
  }

  float v = 0.f;
  for (int i = tid; i < m; i += 1024) {
    unsigned int kv = useLds ? skeys[i] : kb[i];
    if (ta || kv > T) v += softplus0(key2f(kv));
  }
#pragma unroll
  for (int o = 32; o > 0; o >>= 1) v += __shfl_down(v, o);
  if (lane == 0) wred[wvi] = v;
  __syncthreads();
  if (tid == 0) {
    float sum = 0.f;
#pragma unroll
    for (int wv = 0; wv < 16; ++wv) sum += wred[wv];
    if (!ta) sum += (float)k * softplus0(key2f(T));
    ws->neg_sum[b] = sum;
    __threadfence();
    int old = atomicAdd(&ws->done, 1);
    sh_last = (old == NB - 1) ? 1 : 0;
  }
  __syncthreads();
  if (sh_last && tid == 0) {
    __threadfence();
    float cls_s = 0.f, reg_s = 0.f, np_s = 0.f;
    for (int bb = 0; bb < NB; ++bb) {
      int np = ws->npos[bb];
      float pos_l = (np > 0) ? 5.f * ws->pos_sum[bb] / (float)np : 0.f;
      int M = ws->neg_cnt[bb];
      float kcnt = fminf((float)M, (float)KTOP);
      float neg_l = (kcnt > 0.f) ? ws->neg_sum[bb] / fmaxf(kcnt, 1.f) : 0.f;
      float reg_l = (np > 0) ? ws->reg_sum[bb] / (4.f * (float)np) : 0.f;
      cls_s += pos_l + neg_l;
      reg_s += reg_l;
      np_s += (float)np;
    }
    float cls = cls_s * 0.25f;
    float reg = reg_s * 0.25f;
    out[0] = cls + 0.5f * reg;
    out[1] = cls;
    out[2] = reg;
    out[3] = np_s;
  }
}

extern "C" void kernel_launch(void* const* d_in, const int* in_sizes, int n_in,
                              void* d_out, int out_size, void* d_ws, size_t ws_size,
                              hipStream_t stream) {
  const float* pred = (const float*)d_in[0];
  const float* tgt  = (const float*)d_in[1];
  WsHeader* ws = (WsHeader*)d_ws;
  char* base = (char*)d_ws + ((sizeof(WsHeader) + 255) / 256) * 256;
  unsigned int* keys = (unsigned int*)base;
  unsigned int* bucket = (unsigned int*)(base + (size_t)NB * NCELL * 4);
  float* out = (float*)d_out;

  hipMemsetAsync(d_ws, 0, sizeof(WsHeader), stream);
  hipLaunchKernelGGL(main_kernel, dim3(MBLK, NB), dim3(256), 0, stream, pred, tgt, ws, keys);
  hipLaunchKernelGGL(compact_kernel, dim3(81, NB), dim3(256), 0, stream, keys, ws, bucket);
  hipLaunchKernelGGL(final_kernel, dim3(NB), dim3(1024), 0, stream, bucket, ws, out);
}

// Round 3
// 103.372 us; speedup vs baseline: 1.5036x; 1.0465x over previous
//
#include <hip/hip_runtime.h>
#include <cstdint>
#include <cstddef>

#define NB 4
#define NG 8
#define NCELL 331776   // 48*48*48*3
#define KTOP 800
#define NREP 8         // global histogram replicas to spread atomic traffic
#define CAP 16384      // per-batch tie-bucket capacity (ties <= old ~7.4k candidate count)
#define CPT 8          // cells per thread in main (ILP chains)
#define MBLK 162       // main blocks per batch: 162 * 256 * 8 = NCELL

struct WsHeader {
  float pos_sum[NB];
  float reg_sum[NB];
  int   npos[NB];
  int   neg_cnt[NB];
  int   take_all[NB];
  int   prefix8[NB];            // top-byte threshold bucket j
  int   k_rem[NB];              // KTOP - count(top byte > j)
  float neg_sum[NB];            // tie-side sum (from final)
  float above_sum[NB];          // strictly-above-threshold sum (from compact)
  int   done;
  int   bucket_cnt[NB][16];     // one cacheline per batch
  unsigned int hist[NB][NREP][256];
};

__device__ __forceinline__ float softplus0(float x) {
  // _bce_logits(x, 0) = max(x,0) + log1p(exp(-|x|))
  return fmaxf(x, 0.f) + log1pf(expf(-fabsf(x)));
}
__device__ __forceinline__ unsigned int f2key(float f) {
  unsigned int u = __float_as_uint(f);
  return (u & 0x80000000u) ? ~u : (u | 0x80000000u);
}
__device__ __forceinline__ float key2f(unsigned int k) {
  unsigned int u = (k & 0x80000000u) ? (k & 0x7fffffffu) : ~k;
  return __uint_as_float(u);
}
__device__ __forceinline__ float sl1(float x) {
  float ax = fabsf(x);
  return ax < 1.f ? 0.5f * x * x : ax - 0.5f;
}

// Per-cell loss terms + dense key write + top-byte histogram.
// R3: separable IoU — per-axis overlap extents depend only on (g, anchor, coord),
// so precompute 3x1152-entry LDS tables once per block; inner loop is
// 3 LDS reads + 2 muls per gt. Divides eliminated via cross-multiplied argmax
// compare (denominators > 0; the reference's +1e-6 is provably absorbed since
// union >= 125 and ulp(125) = 9.5e-6 > 1e-6, so comparisons are on identical
// rationals; flips only possible at rounded-ties — measure-zero, fixed input).
// NOTE (R1 lesson): no device-scope fences in this wide kernel — cross-XCD
// visibility of keys/hist comes from the kernel boundary.
__global__ __launch_bounds__(256) void main_kernel(const float* __restrict__ pred,
                                                   const float* __restrict__ tgt,
                                                   WsHeader* __restrict__ ws,
                                                   unsigned int* __restrict__ keys) {
  __shared__ float gt[NG * 4];
  __shared__ float tabx[NG * 3 * 48];
  __shared__ float taby[NG * 3 * 48];
  __shared__ float tabz[NG * 3 * 48];
  __shared__ float un3[NG * 3];                // an^3 + gd^3 per (g,a)
  __shared__ unsigned int lhist[4 * 257];      // 4 replicas, stride 257
  __shared__ float s_psum, s_rsum;
  __shared__ int s_np;
  const int b = blockIdx.y;
  const int tid = threadIdx.x;
  const int cell0 = blockIdx.x * (256 * CPT);  // 2048 consecutive cells per block

  if (tid < NG * 4) gt[tid] = tgt[b * NG * 4 + tid];
  for (int e = tid; e < 4 * 257; e += 256) lhist[e] = 0u;
  if (tid == 0) { s_psum = 0.f; s_rsum = 0.f; s_np = 0; }
  __syncthreads();

  // build per-axis extent tables: e = (g*3 + a)*48 + coord
  for (int e = tid; e < NG * 3 * 48; e += 256) {
    int g = e / 144; int r = e - g * 144; int a = r / 48; int coord = r - a * 48;
    float c = coord * 4.f + 2.f;
    float an = (a == 0) ? 5.f : ((a == 1) ? 10.f : 20.f);
    float r1 = an * 0.5f;
    float r2 = gt[g * 4 + 3] * 0.5f;
    float gx = gt[g * 4 + 0], gy = gt[g * 4 + 1], gz = gt[g * 4 + 2];
    tabx[e] = fmaxf(fminf(c + r1, gx + r2) - fmaxf(c - r1, gx - r2), 0.f);
    taby[e] = fmaxf(fminf(c + r1, gy + r2) - fmaxf(c - r1, gy - r2), 0.f);
    tabz[e] = fmaxf(fminf(c + r1, gz + r2) - fmaxf(c - r1, gz - r2), 0.f);
  }
  if (tid < NG * 3) {
    int g = tid / 3; int a = tid - 3 * g;
    float an = (a == 0) ? 5.f : ((a == 1) ? 10.f : 20.f);
    float gd = gt[g * 4 + 3];
    un3[tid] = an * an * an + gd * gd * gd;
  }
  __syncthreads();

  const float* pb = pred + (size_t)b * NCELL * 5;

  // issue all CPT conf loads up-front (independent chains)
  float conf[CPT];
#pragma unroll
  for (int j = 0; j < CPT; ++j)
    conf[j] = pb[(size_t)(cell0 + j * 256 + tid) * 5];

#pragma unroll
  for (int j = 0; j < CPT; ++j) {
    const int i = cell0 + j * 256 + tid;
    int a = i % 3; int t = i / 3;
    int w = t % 48; t /= 48;
    int h = t % 48; int d = t / 48;
    const int a48 = a * 48;

    // g = 0 init, then division-free running argmax over g = 1..7
    float biv, bug; int arg = 0;
    {
      float iv = (tabx[a48 + w] * taby[a48 + h]) * tabz[a48 + d];
      biv = iv; bug = un3[a] - iv;
    }
#pragma unroll
    for (int g = 1; g < NG; ++g) {
      const int base = g * 144 + a48;
      float iv = (tabx[base + w] * taby[base + h]) * tabz[base + d];
      float ug = un3[g * 3 + a] - iv;
      if (iv * bug > biv * ug) { biv = iv; bug = ug; arg = g; }   // iou_g > best
    }
    const bool pos = biv > 0.5f * bug;     // iou > 0.5
    const bool neg = biv < 0.02f * bug;    // iou < 0.02
    const float cf = conf[j];

    unsigned int key = 0u;   // sentinel: -NaN bit pattern, unreachable as real key
    if (neg) {
      key = f2key(cf);
      atomicAdd(&lhist[(tid & 3) * 257 + (key >> 24)], 1u);
    }
    keys[(size_t)b * NCELL + i] = key;

    if (pos) {
      const size_t base = (size_t)i * 5;
      const float an = (a == 0) ? 5.f : ((a == 1) ? 10.f : 20.f);
      const float cx = w * 4.f + 2.f, cy = h * 4.f + 2.f, cz = d * 4.f + 2.f;
      float bce1 = fmaxf(cf, 0.f) - cf + log1pf(expf(-fabsf(cf)));
      float mgx = gt[arg * 4 + 0], mgy = gt[arg * 4 + 1], mgz = gt[arg * 4 + 2], mgd = gt[arg * 4 + 3];
      float t0 = (mgx - cx) / an, t1 = (mgy - cy) / an, t2 = (mgz - cz) / an;
      float t3 = logf(mgd / an);
      float d0 = pb[base + 1] - t0;
      float d1 = pb[base + 2] - t1;
      float d2 = pb[base + 3] - t2;
      float d3 = pb[base + 4] - t3;
      float rl = sl1(d0) + sl1(d1) + sl1(d2) + sl1(d3);
      atomicAdd(&s_psum, bce1);
      atomicAdd(&s_rsum, rl);
      atomicAdd(&s_np, 1);
    }
  }
  __syncthreads();

  unsigned int c = lhist[tid] + lhist[257 + tid] + lhist[514 + tid] + lhist[771 + tid];
  if (c) atomicAdd(&ws->hist[b][blockIdx.x & (NREP - 1)][tid], c);
  if (tid == 0 && s_np > 0) {        // rare: fire-and-forget, most blocks skip
    atomicAdd(&ws->pos_sum[b], s_psum);
    atomicAdd(&ws->reg_sum[b], s_rsum);
    atomicAdd(&ws->npos[b], s_np);
  }
}

// Grid-parallel: each block redundantly finds the 8-bit threshold bucket j from
// the histogram (wave-shfl suffix scan), then:
//   - keys with top byte  > j are ALL in the top-800 (<=799 of them): softplus-sum
//     them here into above_sum (one atomicAdd per block);
//   - keys with top byte == j (the ties) are compacted into the bucket buffer
//     for final's exact refinement.
// Publishes j and k_rem so final skips its degenerate radix pass 0.
__global__ __launch_bounds__(256) void compact_kernel(const unsigned int* __restrict__ keys,
                                                      WsHeader* __restrict__ ws,
                                                      unsigned int* __restrict__ bucket) {
  const int b = blockIdx.y;
  const int tid = threadIdx.x;
  const int lane = tid & 63;
  const int wvi = tid >> 6;
  __shared__ unsigned int A[256];
  __shared__ unsigned int wtot[4];
  __shared__ float swred[4];
  __shared__ int sh_j, sh_base;

  // ---- phase 1: global hist -> suffix scan -> threshold bucket j ----
  unsigned int s = 0;
#pragma unroll
  for (int r = 0; r < NREP; ++r) s += ws->hist[b][r][tid];
  unsigned int v = s;
#pragma unroll
  for (int o = 1; o < 64; o <<= 1) {               // in-wave inclusive suffix scan
    unsigned int t = __shfl_down(v, o);
    if (lane + o < 64) v += t;
  }
  if (lane == 0) wtot[wvi] = v;                    // wave total
  __syncthreads();
  unsigned int carry = 0;
#pragma unroll
  for (int w2 = 0; w2 < 4; ++w2) carry += (w2 > wvi) ? wtot[w2] : 0u;
  v += carry;
  A[tid] = v;
  __syncthreads();
  const int M = (int)A[0];
  const bool ta = (M < KTOP);
  if (!ta && A[tid] >= (unsigned)KTOP && (tid == 255 || A[tid + 1] < (unsigned)KTOP))
    sh_j = tid;
  __syncthreads();
  const unsigned int jthr = ta ? 0u : (unsigned int)sh_j;
  if (tid == 0 && blockIdx.x == 0) {
    ws->neg_cnt[b] = M;
    ws->take_all[b] = ta ? 1 : 0;
    ws->prefix8[b] = (int)jthr;
    int above = (!ta && jthr < 255u) ? (int)A[jthr + 1] : 0;
    ws->k_rem[b] = ta ? 0 : (KTOP - above);
  }

  // ---- phase 2: classify; sum strictly-above, compact ties ----
  const uint4* k4 = (const uint4*)(keys + (size_t)b * NCELL);
  const int base4 = blockIdx.x * 1024;   // 81 blocks x 1024 uint4 = NCELL/4
  int cnt = 0;
  float asum = 0.f;
#pragma unroll
  for (int it = 0; it < 4; ++it) {
    uint4 kk = k4[base4 + it * 256 + tid];
    unsigned int kv;
#define CLASSIFY(KV)                                                        \
    kv = (KV);                                                              \
    if (kv != 0u) {                                                         \
      unsigned int tb = kv >> 24;                                           \
      if (ta || tb == jthr) ++cnt;                                          \
      else if (tb > jthr) asum += softplus0(key2f(kv));                     \
    }
    CLASSIFY(kk.x) CLASSIFY(kk.y) CLASSIFY(kk.z) CLASSIFY(kk.w)
#undef CLASSIFY
  }
  unsigned int pv = (unsigned int)cnt;
#pragma unroll
  for (int o = 1; o < 64; o <<= 1) {               // in-wave inclusive prefix scan
    unsigned int t = __shfl_up(pv, o);
    if (lane >= o) pv += t;
  }
  if (lane == 63) wtot[wvi] = pv;                  // safe: phase-1 wtot reads done pre-A-barrier
  __syncthreads();
  unsigned int pcarry = 0, ptot = 0;
#pragma unroll
  for (int w2 = 0; w2 < 4; ++w2) {
    ptot += wtot[w2];
    pcarry += (w2 < wvi) ? wtot[w2] : 0u;
  }
  if (tid == 0) sh_base = ptot ? atomicAdd(&ws->bucket_cnt[b][0], (int)ptot) : 0;
  __syncthreads();
  int off = sh_base + (int)(pv + pcarry) - cnt;    // exclusive rank + block base
#pragma unroll
  for (int it = 0; it < 4; ++it) {
    uint4 kk = k4[base4 + it * 256 + tid];
    unsigned int kv;
#define EMIT(KV)                                                            \
    kv = (KV);                                                              \
    if (kv != 0u && (ta || (kv >> 24) == jthr)) {                           \
      if (off < CAP) bucket[(size_t)b * CAP + off] = kv;                    \
      ++off;                                                                \
    }
    EMIT(kk.x) EMIT(kk.y) EMIT(kk.z) EMIT(kk.w)
#undef EMIT
  }

  // ---- phase 3: block-reduce above_sum, one atomic per block ----
#pragma unroll
  for (int o = 32; o > 0; o >>= 1) asum += __shfl_down(asum, o);
  if (lane == 0) swred[wvi] = asum;
  __syncthreads();
  if (tid == 0) {
    float tsum = swred[0] + swred[1] + swred[2] + swred[3];
    if (tsum != 0.f) atomicAdd(&ws->above_sum[b], tsum);
  }
}

// One block per batch: exact top-KTOP refinement among the TIE candidates only
// (top byte == j; strictly-above already summed by compact). Two 12-bit radix
// passes (4096-bin LDS hist) over the 24 remaining key bits; candidates read
// straight from L2 (small set, no LDS staging). Last block also combines.
__global__ __launch_bounds__(1024) void final_kernel(const unsigned int* __restrict__ bucket,
                                                     WsHeader* __restrict__ ws,
                                                     float* __restrict__ out) {
  const int b = blockIdx.x;
  const int tid = threadIdx.x;
  const int lane = tid & 63;
  const int wvi = tid >> 6;
  __shared__ unsigned int h[4096];
  __shared__ unsigned int A[4096];
  __shared__ unsigned int wt16[16];
  __shared__ float wred[16];
  __shared__ int sh_j, sh_last;

  int m = ws->bucket_cnt[b][0]; if (m > CAP) m = CAP;
  const bool ta = ws->take_all[b] != 0;
  const unsigned int* kb = bucket + (size_t)b * CAP;

  unsigned int T = 0u;
  int k = 0;
  if (!ta) {
    k = ws->k_rem[b];
    unsigned int P = ((unsigned int)ws->prefix8[b]) << 24;
    unsigned int jj1 = 0;
#pragma unroll
    for (int pass = 0; pass < 2; ++pass) {
      h[tid] = 0u; h[tid + 1024] = 0u; h[tid + 2048] = 0u; h[tid + 3072] = 0u;
      __syncthreads();
      for (int i = tid; i < m; i += 1024) {
        unsigned int kv = kb[i];
        if (pass == 0) atomicAdd(&h[(kv >> 12) & 4095u], 1u);
        else if (((kv >> 12) & 4095u) == jj1) atomicAdd(&h[kv & 4095u], 1u);
      }
      __syncthreads();
      // suffix scan over 4096 bins: thread t owns bins [4t, 4t+3]
      unsigned int h0 = h[4 * tid], h1 = h[4 * tid + 1], h2 = h[4 * tid + 2], h3 = h[4 * tid + 3];
      unsigned int s3 = h3, s2 = h2 + s3, s1 = h1 + s2, s0 = h0 + s1;
      unsigned int tot = s0, vv = tot;
#pragma unroll
      for (int o = 1; o < 64; o <<= 1) {
        unsigned int t = __shfl_down(vv, o);
        if (lane + o < 64) vv += t;
      }
      if (lane == 0) wt16[wvi] = vv;
      __syncthreads();
      unsigned int cr = 0;
#pragma unroll
      for (int w2 = 0; w2 < 16; ++w2) cr += (w2 > wvi) ? wt16[w2] : 0u;
      unsigned int hi = cr + (vv - tot);           // suffix from strictly-higher threads
      A[4 * tid] = hi + s0; A[4 * tid + 1] = hi + s1; A[4 * tid + 2] = hi + s2; A[4 * tid + 3] = hi + s3;
      __syncthreads();
#pragma unroll
      for (int q = 0; q < 4; ++q) {
        int bin = 4 * tid + q;
        if (A[bin] >= (unsigned)k && (bin == 4095 || A[bin + 1] < (unsigned)k)) sh_j = bin;
      }
      __syncthreads();
      const int jj = sh_j;
      k -= (jj == 4095) ? 0 : (int)A[jj + 1];      // remove strictly-greater bins
      if (pass == 0) { jj1 = (unsigned)jj; P |= ((unsigned int)jj) << 12; }
      else           { P |= (unsigned int)jj; }
      // no trailing barrier: next pass's h-zero + barrier orders A/sh_j reuse
    }
    T = P;   // exact threshold key; k = #ties to take at T
  }

  float v = 0.f;
  for (int i = tid; i < m; i += 1024) {
    unsigned int kv = kb[i];
    if (ta || kv > T) v += softplus0(key2f(kv));
  }
#pragma unroll
  for (int o = 32; o > 0; o >>= 1) v += __shfl_down(v, o);
  if (lane == 0) wred[wvi] = v;
  __syncthreads();
  if (tid == 0) {
    float sum = 0.f;
#pragma unroll
    for (int wv = 0; wv < 16; ++wv) sum += wred[wv];
    if (!ta) sum += (float)k * softplus0(key2f(T));
    ws->neg_sum[b] = sum;
    __threadfence();
    int old = atomicAdd(&ws->done, 1);
    sh_last = (old == NB - 1) ? 1 : 0;
  }
  __syncthreads();
  if (sh_last && tid == 0) {
    __threadfence();
    float cls_s = 0.f, reg_s = 0.f, np_s = 0.f;
    for (int bb = 0; bb < NB; ++bb) {
      int np = ws->npos[bb];
      float pos_l = (np > 0) ? 5.f * ws->pos_sum[bb] / (float)np : 0.f;
      int M = ws->neg_cnt[bb];
      float kcnt = fminf((float)M, (float)KTOP);
      float neg_l = (kcnt > 0.f) ? (ws->neg_sum[bb] + ws->above_sum[bb]) / fmaxf(kcnt, 1.f) : 0.f;
      float reg_l = (np > 0) ? ws->reg_sum[bb] / (4.f * (float)np) : 0.f;
      cls_s += pos_l + neg_l;
      reg_s += reg_l;
      np_s += (float)np;
    }
    float cls = cls_s * 0.25f;
    float reg = reg_s * 0.25f;
    out[0] = cls + 0.5f * reg;
    out[1] = cls;
    out[2] = reg;
    out[3] = np_s;
  }
}

extern "C" void kernel_launch(void* const* d_in, const int* in_sizes, int n_in,
                              void* d_out, int out_size, void* d_ws, size_t ws_size,
                              hipStream_t stream) {
  const float* pred = (const float*)d_in[0];
  const float* tgt  = (const float*)d_in[1];
  WsHeader* ws = (WsHeader*)d_ws;
  char* base = (char*)d_ws + ((sizeof(WsHeader) + 255) / 256) * 256;
  unsigned int* keys = (unsigned int*)base;
  unsigned int* bucket = (unsigned int*)(base + (size_t)NB * NCELL * 4);
  float* out = (float*)d_out;

  hipMemsetAsync(d_ws, 0, sizeof(WsHeader), stream);
  hipLaunchKernelGGL(main_kernel, dim3(MBLK, NB), dim3(256), 0, stream, pred, tgt, ws, keys);
  hipLaunchKernelGGL(compact_kernel, dim3(81, NB), dim3(256), 0, stream, keys, ws, bucket);
  hipLaunchKernelGGL(final_kernel, dim3(NB), dim3(1024), 0, stream, bucket, ws, out);
}

// Round 4
// 101.584 us; speedup vs baseline: 1.5300x; 1.0176x over previous
//
#include <hip/hip_runtime.h>
#include <cstdint>
#include <cstddef>

#define NB 4
#define NG 8
#define NCELL 331776   // 48*48*48*3
#define KTOP 800
#define NREP 8         // global histogram replicas to spread atomic traffic
#define CAP 16384      // per-batch tie-bucket capacity
#define CPT 8          // cells per thread in main (d-direction)
#define MBLK 162       // main blocks per batch: 27 parts x 6 d-octaves

struct WsHeader {
  float pos_sum[NB];
  float reg_sum[NB];
  int   npos[NB];
  int   neg_cnt[NB];
  int   take_all[NB];
  int   prefix8[NB];            // top-byte threshold bucket j
  int   k_rem[NB];              // KTOP - count(top byte > j)
  float neg_sum[NB];            // tie-side sum (from final)
  float above_sum[NB];          // strictly-above-threshold sum (from compact)
  int   done;
  int   bucket_cnt[NB][16];     // one cacheline per batch
  unsigned int hist[NB][NREP][256];
};

__device__ __forceinline__ float softplus0(float x) {
  // _bce_logits(x, 0) = max(x,0) + log1p(exp(-|x|))
  return fmaxf(x, 0.f) + log1pf(expf(-fabsf(x)));
}
__device__ __forceinline__ unsigned int f2key(float f) {
  unsigned int u = __float_as_uint(f);
  return (u & 0x80000000u) ? ~u : (u | 0x80000000u);
}
__device__ __forceinline__ float key2f(unsigned int k) {
  unsigned int u = (k & 0x80000000u) ? (k & 0x7fffffffu) : ~k;
  return __uint_as_float(u);
}
__device__ __forceinline__ float sl1(float x) {
  float ax = fabsf(x);
  return ax < 1.f ? 0.5f * x * x : ax - 0.5f;
}

// Per-cell loss terms + dense key write + top-byte histogram.
// R4: cell->thread mapping groups 8 cells sharing (a,w,h), varying d.
// tabx/taby/un3 hoisted to registers once per gt (txy[g]=tx*ty precomputed);
// only tabz remains in the inner loop: LDS reads 24 -> 11 per cell, the pipe
// that dominated main (R4 arithmetic: 32M lane-reads ~ 4.5us > VALU 1.7us).
// Coalescing preserved: per q, lanes sweep consecutive idx.
// FP bit-identical to R3: (tx*ty)*tz same association, argmax order unchanged.
// NOTE (R1 lesson): no device-scope fences in this wide kernel — cross-XCD
// visibility of keys/hist comes from the kernel boundary.
__global__ __launch_bounds__(256) void main_kernel(const float* __restrict__ pred,
                                                   const float* __restrict__ tgt,
                                                   WsHeader* __restrict__ ws,
                                                   unsigned int* __restrict__ keys) {
  __shared__ float gt[NG * 4];
  __shared__ float tabx[NG * 3 * 48];
  __shared__ float taby[NG * 3 * 48];
  __shared__ float tabz[NG * 3 * 48];
  __shared__ float un3[NG * 3];                // an^3 + gd^3 per (g,a)
  __shared__ unsigned int lhist[4 * 257];      // 4 replicas, stride 257
  __shared__ float s_psum, s_rsum;
  __shared__ int s_np;
  const int b = blockIdx.y;
  const int tid = threadIdx.x;
  const int part = blockIdx.x % 27;            // 27 * 256 = 6912 = 48*48*3 (one d-slab)
  const int d0 = (blockIdx.x / 27) * CPT;      // d-octave base

  if (tid < NG * 4) gt[tid] = tgt[b * NG * 4 + tid];
  for (int e = tid; e < 4 * 257; e += 256) lhist[e] = 0u;
  if (tid == 0) { s_psum = 0.f; s_rsum = 0.f; s_np = 0; }
  __syncthreads();

  // build per-axis extent tables: e = (g*3 + a)*48 + coord
  for (int e = tid; e < NG * 3 * 48; e += 256) {
    int g = e / 144; int r = e - g * 144; int a = r / 48; int coord = r - a * 48;
    float c = coord * 4.f + 2.f;
    float an = (a == 0) ? 5.f : ((a == 1) ? 10.f : 20.f);
    float r1 = an * 0.5f;
    float r2 = gt[g * 4 + 3] * 0.5f;
    float gx = gt[g * 4 + 0], gy = gt[g * 4 + 1], gz = gt[g * 4 + 2];
    tabx[e] = fmaxf(fminf(c + r1, gx + r2) - fmaxf(c - r1, gx - r2), 0.f);
    taby[e] = fmaxf(fminf(c + r1, gy + r2) - fmaxf(c - r1, gy - r2), 0.f);
    tabz[e] = fmaxf(fminf(c + r1, gz + r2) - fmaxf(c - r1, gz - r2), 0.f);
  }
  if (tid < NG * 3) {
    int g = tid / 3; int a = tid - 3 * g;
    float an = (a == 0) ? 5.f : ((a == 1) ? 10.f : 20.f);
    float gd = gt[g * 4 + 3];
    un3[tid] = an * an * an + gd * gd * gd;
  }
  __syncthreads();

  // this thread's fixed (a, w, h); d varies over the octave
  const int idx = part * 256 + tid;            // = h*144 + w*3 + a
  const int a = idx % 3;
  const int wh = idx / 3;
  const int w = wh % 48;
  const int h = wh / 48;
  const int a48 = a * 48;
  const float an = (a == 0) ? 5.f : ((a == 1) ? 10.f : 20.f);
  const float cx = w * 4.f + 2.f, cy = h * 4.f + 2.f;

  const float* pb = pred + (size_t)b * NCELL * 5;

  // issue all CPT conf loads up-front (independent chains)
  float conf[CPT];
#pragma unroll
  for (int q = 0; q < CPT; ++q)
    conf[q] = pb[(size_t)((d0 + q) * 6912 + idx) * 5];

  // hoist per-gt x/y extents and unions into registers
  float txy[NG], un[NG];
#pragma unroll
  for (int g = 0; g < NG; ++g) {
    float tx = tabx[g * 144 + a48 + w];
    float ty = taby[g * 144 + a48 + h];
    txy[g] = tx * ty;
    un[g] = un3[g * 3 + a];
  }

#pragma unroll
  for (int q = 0; q < CPT; ++q) {
    const int dq = d0 + q;
    const int i = dq * 6912 + idx;

    // g = 0 init, then division-free running argmax over g = 1..7
    float biv, bug; int arg = 0;
    {
      float iv = txy[0] * tabz[a48 + dq];
      biv = iv; bug = un[0] - iv;
    }
#pragma unroll
    for (int g = 1; g < NG; ++g) {
      float iv = txy[g] * tabz[g * 144 + a48 + dq];
      float ug = un[g] - iv;
      if (iv * bug > biv * ug) { biv = iv; bug = ug; arg = g; }   // iou_g > best
    }
    const bool pos = biv > 0.5f * bug;     // iou > 0.5
    const bool neg = biv < 0.02f * bug;    // iou < 0.02
    const float cf = conf[q];

    unsigned int key = 0u;   // sentinel: unreachable as real key
    if (neg) {
      key = f2key(cf);
      atomicAdd(&lhist[(tid & 3) * 257 + (key >> 24)], 1u);
    }
    keys[(size_t)b * NCELL + i] = key;

    if (pos) {
      const size_t base = (size_t)i * 5;
      const float cz = dq * 4.f + 2.f;
      float bce1 = fmaxf(cf, 0.f) - cf + log1pf(expf(-fabsf(cf)));
      float mgx = gt[arg * 4 + 0], mgy = gt[arg * 4 + 1], mgz = gt[arg * 4 + 2], mgd = gt[arg * 4 + 3];
      float t0 = (mgx - cx) / an, t1 = (mgy - cy) / an, t2 = (mgz - cz) / an;
      float t3 = logf(mgd / an);
      float d0f = pb[base + 1] - t0;
      float d1f = pb[base + 2] - t1;
      float d2f = pb[base + 3] - t2;
      float d3f = pb[base + 4] - t3;
      float rl = sl1(d0f) + sl1(d1f) + sl1(d2f) + sl1(d3f);
      atomicAdd(&s_psum, bce1);
      atomicAdd(&s_rsum, rl);
      atomicAdd(&s_np, 1);
    }
  }
  __syncthreads();

  unsigned int c = lhist[tid] + lhist[257 + tid] + lhist[514 + tid] + lhist[771 + tid];
  if (c) atomicAdd(&ws->hist[b][blockIdx.x & (NREP - 1)][tid], c);
  if (tid == 0 && s_np > 0) {        // rare: fire-and-forget, most blocks skip
    atomicAdd(&ws->pos_sum[b], s_psum);
    atomicAdd(&ws->reg_sum[b], s_rsum);
    atomicAdd(&ws->npos[b], s_np);
  }
}

// Grid-parallel: each block redundantly finds the 8-bit threshold bucket j from
// the histogram (wave-shfl suffix scan), then:
//   - keys with top byte  > j are ALL in the top-800 (<=799 of them): softplus-sum
//     them here into above_sum (one atomicAdd per block);
//   - keys with top byte == j (the ties) are compacted into the bucket buffer
//     for final's exact refinement.
// Publishes j and k_rem so final skips its degenerate radix pass 0.
__global__ __launch_bounds__(256) void compact_kernel(const unsigned int* __restrict__ keys,
                                                      WsHeader* __restrict__ ws,
                                                      unsigned int* __restrict__ bucket) {
  const int b = blockIdx.y;
  const int tid = threadIdx.x;
  const int lane = tid & 63;
  const int wvi = tid >> 6;
  __shared__ unsigned int A[256];
  __shared__ unsigned int wtot[4];
  __shared__ float swred[4];
  __shared__ int sh_j, sh_base;

  // ---- phase 1: global hist -> suffix scan -> threshold bucket j ----
  unsigned int s = 0;
#pragma unroll
  for (int r = 0; r < NREP; ++r) s += ws->hist[b][r][tid];
  unsigned int v = s;
#pragma unroll
  for (int o = 1; o < 64; o <<= 1) {               // in-wave inclusive suffix scan
    unsigned int t = __shfl_down(v, o);
    if (lane + o < 64) v += t;
  }
  if (lane == 0) wtot[wvi] = v;                    // wave total
  __syncthreads();
  unsigned int carry = 0;
#pragma unroll
  for (int w2 = 0; w2 < 4; ++w2) carry += (w2 > wvi) ? wtot[w2] : 0u;
  v += carry;
  A[tid] = v;
  __syncthreads();
  const int M = (int)A[0];
  const bool ta = (M < KTOP);
  if (!ta && A[tid] >= (unsigned)KTOP && (tid == 255 || A[tid + 1] < (unsigned)KTOP))
    sh_j = tid;
  __syncthreads();
  const unsigned int jthr = ta ? 0u : (unsigned int)sh_j;
  if (tid == 0 && blockIdx.x == 0) {
    ws->neg_cnt[b] = M;
    ws->take_all[b] = ta ? 1 : 0;
    ws->prefix8[b] = (int)jthr;
    int above = (!ta && jthr < 255u) ? (int)A[jthr + 1] : 0;
    ws->k_rem[b] = ta ? 0 : (KTOP - above);
  }

  // ---- phase 2: classify; sum strictly-above, compact ties ----
  const uint4* k4 = (const uint4*)(keys + (size_t)b * NCELL);
  const int base4 = blockIdx.x * 1024;   // 81 blocks x 1024 uint4 = NCELL/4
  int cnt = 0;
  float asum = 0.f;
#pragma unroll
  for (int it = 0; it < 4; ++it) {
    uint4 kk = k4[base4 + it * 256 + tid];
    unsigned int kv;
#define CLASSIFY(KV)                                                        \
    kv = (KV);                                                              \
    if (kv != 0u) {                                                         \
      unsigned int tb = kv >> 24;                                           \
      if (ta || tb == jthr) ++cnt;                                          \
      else if (tb > jthr) asum += softplus0(key2f(kv));                     \
    }
    CLASSIFY(kk.x) CLASSIFY(kk.y) CLASSIFY(kk.z) CLASSIFY(kk.w)
#undef CLASSIFY
  }
  unsigned int pv = (unsigned int)cnt;
#pragma unroll
  for (int o = 1; o < 64; o <<= 1) {               // in-wave inclusive prefix scan
    unsigned int t = __shfl_up(pv, o);
    if (lane >= o) pv += t;
  }
  if (lane == 63) wtot[wvi] = pv;                  // safe: phase-1 wtot reads done pre-A-barrier
  __syncthreads();
  unsigned int pcarry = 0, ptot = 0;
#pragma unroll
  for (int w2 = 0; w2 < 4; ++w2) {
    ptot += wtot[w2];
    pcarry += (w2 < wvi) ? wtot[w2] : 0u;
  }
  if (tid == 0) sh_base = ptot ? atomicAdd(&ws->bucket_cnt[b][0], (int)ptot) : 0;
  __syncthreads();
  int off = sh_base + (int)(pv + pcarry) - cnt;    // exclusive rank + block base
#pragma unroll
  for (int it = 0; it < 4; ++it) {
    uint4 kk = k4[base4 + it * 256 + tid];
    unsigned int kv;
#define EMIT(KV)                                                            \
    kv = (KV);                                                              \
    if (kv != 0u && (ta || (kv >> 24) == jthr)) {                           \
      if (off < CAP) bucket[(size_t)b * CAP + off] = kv;                    \
      ++off;                                                                \
    }
    EMIT(kk.x) EMIT(kk.y) EMIT(kk.z) EMIT(kk.w)
#undef EMIT
  }

  // ---- phase 3: block-reduce above_sum, one atomic per block ----
#pragma unroll
  for (int o = 32; o > 0; o >>= 1) asum += __shfl_down(asum, o);
  if (lane == 0) swred[wvi] = asum;
  __syncthreads();
  if (tid == 0) {
    float tsum = swred[0] + swred[1] + swred[2] + swred[3];
    if (tsum != 0.f) atomicAdd(&ws->above_sum[b], tsum);
  }
}

// One block per batch: exact top-KTOP refinement among the TIE candidates only
// (top byte == j; strictly-above already summed by compact). Two 12-bit radix
// passes (4096-bin LDS hist) over the 24 remaining key bits; candidates read
// straight from L2 (small set, no LDS staging). Last block also combines.
__global__ __launch_bounds__(1024) void final_kernel(const unsigned int* __restrict__ bucket,
                                                     WsHeader* __restrict__ ws,
                                                     float* __restrict__ out) {
  const int b = blockIdx.x;
  const int tid = threadIdx.x;
  const int lane = tid & 63;
  const int wvi = tid >> 6;
  __shared__ unsigned int h[4096];
  __shared__ unsigned int A[4096];
  __shared__ unsigned int wt16[16];
  __shared__ float wred[16];
  __shared__ int sh_j, sh_last;

  int m = ws->bucket_cnt[b][0]; if (m > CAP) m = CAP;
  const bool ta = ws->take_all[b] != 0;
  const unsigned int* kb = bucket + (size_t)b * CAP;

  unsigned int T = 0u;
  int k = 0;
  if (!ta) {
    k = ws->k_rem[b];
    unsigned int P = ((unsigned int)ws->prefix8[b]) << 24;
    unsigned int jj1 = 0;
#pragma unroll
    for (int pass = 0; pass < 2; ++pass) {
      h[tid] = 0u; h[tid + 1024] = 0u; h[tid + 2048] = 0u; h[tid + 3072] = 0u;
      __syncthreads();
      for (int i = tid; i < m; i += 1024) {
        unsigned int kv = kb[i];
        if (pass == 0) atomicAdd(&h[(kv >> 12) & 4095u], 1u);
        else if (((kv >> 12) & 4095u) == jj1) atomicAdd(&h[kv & 4095u], 1u);
      }
      __syncthreads();
      // suffix scan over 4096 bins: thread t owns bins [4t, 4t+3]
      unsigned int h0 = h[4 * tid], h1 = h[4 * tid + 1], h2 = h[4 * tid + 2], h3 = h[4 * tid + 3];
      unsigned int s3 = h3, s2 = h2 + s3, s1 = h1 + s2, s0 = h0 + s1;
      unsigned int tot = s0, vv = tot;
#pragma unroll
      for (int o = 1; o < 64; o <<= 1) {
        unsigned int t = __shfl_down(vv, o);
        if (lane + o < 64) vv += t;
      }
      if (lane == 0) wt16[wvi] = vv;
      __syncthreads();
      unsigned int cr = 0;
#pragma unroll
      for (int w2 = 0; w2 < 16; ++w2) cr += (w2 > wvi) ? wt16[w2] : 0u;
      unsigned int hi = cr + (vv - tot);           // suffix from strictly-higher threads
      A[4 * tid] = hi + s0; A[4 * tid + 1] = hi + s1; A[4 * tid + 2] = hi + s2; A[4 * tid + 3] = hi + s3;
      __syncthreads();
#pragma unroll
      for (int q = 0; q < 4; ++q) {
        int bin = 4 * tid + q;
        if (A[bin] >= (unsigned)k && (bin == 4095 || A[bin + 1] < (unsigned)k)) sh_j = bin;
      }
      __syncthreads();
      const int jj = sh_j;
      k -= (jj == 4095) ? 0 : (int)A[jj + 1];      // remove strictly-greater bins
      if (pass == 0) { jj1 = (unsigned)jj; P |= ((unsigned int)jj) << 12; }
      else           { P |= (unsigned int)jj; }
      // no trailing barrier: next pass's h-zero + barrier orders A/sh_j reuse
    }
    T = P;   // exact threshold key; k = #ties to take at T
  }

  float v = 0.f;
  for (int i = tid; i < m; i += 1024) {
    unsigned int kv = kb[i];
    if (ta || kv > T) v += softplus0(key2f(kv));
  }
#pragma unroll
  for (int o = 32; o > 0; o >>= 1) v += __shfl_down(v, o);
  if (lane == 0) wred[wvi] = v;
  __syncthreads();
  if (tid == 0) {
    float sum = 0.f;
#pragma unroll
    for (int wv = 0; wv < 16; ++wv) sum += wred[wv];
    if (!ta) sum += (float)k * softplus0(key2f(T));
    ws->neg_sum[b] = sum;
    __threadfence();
    int old = atomicAdd(&ws->done, 1);
    sh_last = (old == NB - 1) ? 1 : 0;
  }
  __syncthreads();
  if (sh_last && tid == 0) {
    __threadfence();
    float cls_s = 0.f, reg_s = 0.f, np_s = 0.f;
    for (int bb = 0; bb < NB; ++bb) {
      int np = ws->npos[bb];
      float pos_l = (np > 0) ? 5.f * ws->pos_sum[bb] / (float)np : 0.f;
      int M = ws->neg_cnt[bb];
      float kcnt = fminf((float)M, (float)KTOP);
      float neg_l = (kcnt > 0.f) ? (ws->neg_sum[bb] + ws->above_sum[bb]) / fmaxf(kcnt, 1.f) : 0.f;
      float reg_l = (np > 0) ? ws->reg_sum[bb] / (4.f * (float)np) : 0.f;
      cls_s += pos_l + neg_l;
      reg_s += reg_l;
      np_s += (float)np;
    }
    float cls = cls_s * 0.25f;
    float reg = reg_s * 0.25f;
    out[0] = cls + 0.5f * reg;
    out[1] = cls;
    out[2] = reg;
    out[3] = np_s;
  }
}

extern "C" void kernel_launch(void* const* d_in, const int* in_sizes, int n_in,
                              void* d_out, int out_size, void* d_ws, size_t ws_size,
                              hipStream_t stream) {
  const float* pred = (const float*)d_in[0];
  const float* tgt  = (const float*)d_in[1];
  WsHeader* ws = (WsHeader*)d_ws;
  char* base = (char*)d_ws + ((sizeof(WsHeader) + 255) / 256) * 256;
  unsigned int* keys = (unsigned int*)base;
  unsigned int* bucket = (unsigned int*)(base + (size_t)NB * NCELL * 4);
  float* out = (float*)d_out;

  hipMemsetAsync(d_ws, 0, sizeof(WsHeader), stream);
  hipLaunchKernelGGL(main_kernel, dim3(MBLK, NB), dim3(256), 0, stream, pred, tgt, ws, keys);
  hipLaunchKernelGGL(compact_kernel, dim3(81, NB), dim3(256), 0, stream, keys, ws, bucket);
  hipLaunchKernelGGL(final_kernel, dim3(NB), dim3(1024), 0, stream, bucket, ws, out);
}